// Round 1
// baseline (320.957 us; speedup 1.0000x reference)
//
#include <hip/hip_runtime.h>

// CRF forward (log-partition) for SEQ=512, BATCH=1024, TAGS=32, fp32.
//
// exp2-space formulation: A[b,k] = 2^(alpha2[b,k] - c2_b), E[j,k] = 2^(trans2[j,k]).
// Per step: P_j = sum_k E[j,k]*A_k ; A_j <- P_j * 2^(feat2[t,b,j]); renorm every 4 steps.
// Lane = (b, j): 32 lanes per batch, 2 batches per wave64. ds_swizzle broadcasts A_k.

constexpr int SEQ   = 512;
constexpr int BATCH = 1024;
constexpr int TAGS  = 32;

#define LOG2E 1.4426950408889634f
#define LN2   0.6931471805599453f

template <int PAT>
__device__ __forceinline__ float swz(float v) {
  return __int_as_float(__builtin_amdgcn_ds_swizzle(__float_as_int(v), PAT));
}

// broadcast of lane k within each 32-lane group: bit-mode and=0, or=k, xor=0 -> pattern k<<5
#define KSTEP(k, accv) { float a_ = swz<((k) << 5)>(A); accv = fmaf(e[(k)], a_, accv); }

extern "C" __global__ void __launch_bounds__(64) crf_fwd(
    const float* __restrict__ feats, const float* __restrict__ mask,
    const float* __restrict__ trans, float* __restrict__ out) {
  const int lane = threadIdx.x;          // 0..63
  const int tag  = lane & 31;
  const int gtid = blockIdx.x * 64 + lane;  // global (b*32 + tag)
  const int b    = gtid >> 5;

  // Per-lane E row: e[k] = 2^(trans[tag][k] * log2(e)).  NEG rows/cols underflow to exact 0.
  float e[TAGS];
#pragma unroll
  for (int k = 0; k < TAGS; ++k)
    e[k] = __builtin_amdgcn_exp2f(trans[tag * TAGS + k] * LOG2E);
  const float efin = __builtin_amdgcn_exp2f(trans[(TAGS - 1) * TAGS + tag] * LOG2E);

  // alpha0 = NEG everywhere, 0 at tag 30  ->  A = delta(tag==30), c2 = 0
  float A  = (tag == 30) ? 1.0f : 0.0f;
  float c2 = 0.0f;

  // software prefetch, depth 4
  float fp[4], mp[4];
#pragma unroll
  for (int d = 0; d < 4; ++d) {
    fp[d] = feats[d * (BATCH * TAGS) + gtid];
    mp[d] = mask[d * BATCH + b];
  }

#pragma unroll 4
  for (int t = 0; t < SEQ; ++t) {
    const int slot   = t & 3;
    const float fcur = fp[slot];
    const float mcur = mp[slot];
    if (t + 4 < SEQ) {
      fp[slot] = feats[(t + 4) * (BATCH * TAGS) + gtid];
      mp[slot] = mask[(t + 4) * BATCH + b];
    }
    const float F = __builtin_amdgcn_exp2f(fcur * LOG2E);

    float acc0 = 0.f, acc1 = 0.f, acc2 = 0.f, acc3 = 0.f;
    KSTEP(0,  acc0) KSTEP(1,  acc1) KSTEP(2,  acc2) KSTEP(3,  acc3)
    KSTEP(4,  acc0) KSTEP(5,  acc1) KSTEP(6,  acc2) KSTEP(7,  acc3)
    KSTEP(8,  acc0) KSTEP(9,  acc1) KSTEP(10, acc2) KSTEP(11, acc3)
    KSTEP(12, acc0) KSTEP(13, acc1) KSTEP(14, acc2) KSTEP(15, acc3)
    KSTEP(16, acc0) KSTEP(17, acc1) KSTEP(18, acc2) KSTEP(19, acc3)
    KSTEP(20, acc0) KSTEP(21, acc1) KSTEP(22, acc2) KSTEP(23, acc3)
    KSTEP(24, acc0) KSTEP(25, acc1) KSTEP(26, acc2) KSTEP(27, acc3)
    KSTEP(28, acc0) KSTEP(29, acc1) KSTEP(30, acc2) KSTEP(31, acc3)

    const float P  = (acc0 + acc1) + (acc2 + acc3);
    const float An = P * F;
    // mask semantics: m==1 -> take new, m==0 -> keep old (select, avoids NaN from 0*inf)
    A = (mcur != 0.0f) ? An : A;

    if (slot == 3) {
      // renormalize: M = max over the 32 lanes of this batch, butterfly via swizzle-xor
      float M = A;
      M = fmaxf(M, swz<0x041f>(M));
      M = fmaxf(M, swz<0x081f>(M));
      M = fmaxf(M, swz<0x101f>(M));
      M = fmaxf(M, swz<0x201f>(M));
      M = fmaxf(M, swz<0x401f>(M));
      const float r = __builtin_amdgcn_rcpf(M);
      A *= r;
      c2 += __builtin_amdgcn_logf(M);   // log2
    }
  }

  // epilogue: out[b] = ln2 * (c2 + log2( sum_j A_j * 2^(trans2[END][j]) ))
  float v = A * efin;
  v += swz<0x041f>(v);
  v += swz<0x081f>(v);
  v += swz<0x101f>(v);
  v += swz<0x201f>(v);
  v += swz<0x401f>(v);
  const float res = LN2 * (c2 + __builtin_amdgcn_logf(v));
  if (tag == 0) out[b] = res;
}

extern "C" void kernel_launch(void* const* d_in, const int* in_sizes, int n_in,
                              void* d_out, int out_size, void* d_ws, size_t ws_size,
                              hipStream_t stream) {
  const float* feats = (const float*)d_in[0];
  const float* mask  = (const float*)d_in[1];
  const float* trans = (const float*)d_in[2];
  float* out = (float*)d_out;
  dim3 grid(BATCH * TAGS / 64);  // 512 blocks, 1 wave each (2 batches/wave)
  dim3 block(64);
  hipLaunchKernelGGL(crf_fwd, grid, block, 0, stream, feats, mask, trans, out);
}

// Round 2
// 284.593 us; speedup vs baseline: 1.1278x; 1.1278x over previous
//
#include <hip/hip_runtime.h>
#include <stdint.h>

// CRF forward (log-partition), SEQ=512, BATCH=1024, TAGS=32, fp32 in/out.
//
// exp2-space: A[k,b] = 2^(alpha2 - c2_b).  Per step, batched matvec via MFMA:
//   D[j,b] = sum_k E[j,k]*A[k,b]   (mfma_f32_16x16x32_bf16, two j-halves)
//   A_new[j,b] = D[j,b] * 2^(feat2[t,b,j]),  mask-blend, renorm every 4 steps.
//
// sigma-permuted contraction order sig(8q+i) = (i<4 ? 4q+i : 16+4q+i-4) makes
// each lane's C/D outputs exactly its own next-step B-operand slots: zero
// cross-lane data movement in the steady-state step.

constexpr int SEQ   = 512;
constexpr int BATCH = 1024;
constexpr int TAGS  = 32;

#define LOG2E 1.4426950408889634f
#define LN2   0.6931471805599453f

typedef __attribute__((ext_vector_type(8))) short  short8;   // 8 bf16 (4 VGPRs)
typedef __attribute__((ext_vector_type(4))) float  float4v;  // C/D frag

// pack two f32 -> packed bf16 pair (round-half-up), 3 VALU ops
__device__ __forceinline__ unsigned pk_bf16(float x, float y) {
  unsigned xu = __float_as_uint(x) + 0x8000u;
  unsigned yu = __float_as_uint(y) + 0x8000u;
  return __builtin_amdgcn_perm(yu, xu, 0x07060302u);  // [x.hi16, y.hi16]
}

union Frag8 { unsigned u[4]; short8 v; };

extern "C" __global__ void __launch_bounds__(64) crf_mfma(
    const float* __restrict__ feats, const float* __restrict__ mask,
    const float* __restrict__ trans, float* __restrict__ out) {
  const int lane = threadIdx.x;          // 0..63
  const int s    = lane & 15;            // batch-within-wave / MFMA row-col idx
  const int q    = lane >> 4;            // quad 0..3
  const int b    = blockIdx.x * 16 + s;  // global batch

  // sigma: k-slot (q,i) -> tag
  int sig[8];
#pragma unroll
  for (int i = 0; i < 8; ++i) sig[i] = (i < 4) ? (4 * q + i) : (16 + 4 * q + (i - 4));

  // Static A-operands: E rows. e0: rows j = s (0..15); e1: rows j = 16+s.
  // A_op[m=s][k-slot 8q+i] = E[row][sig(i)] = 2^(trans2[row][sig(i)])
  Frag8 e0, e1;
#pragma unroll
  for (int p = 0; p < 4; ++p) {
    float x0 = __builtin_amdgcn_exp2f(trans[s * TAGS + sig[2 * p]] * LOG2E);
    float y0 = __builtin_amdgcn_exp2f(trans[s * TAGS + sig[2 * p + 1]] * LOG2E);
    e0.u[p] = pk_bf16(x0, y0);
    float x1 = __builtin_amdgcn_exp2f(trans[(16 + s) * TAGS + sig[2 * p]] * LOG2E);
    float y1 = __builtin_amdgcn_exp2f(trans[(16 + s) * TAGS + sig[2 * p + 1]] * LOG2E);
    e1.u[p] = pk_bf16(x1, y1);
  }

  // Final-transition weights for the tags this lane holds in D-layout
  float ef0[4], ef1[4];
#pragma unroll
  for (int p = 0; p < 4; ++p) {
    ef0[p] = __builtin_amdgcn_exp2f(trans[31 * TAGS + (4 * q + p)] * LOG2E);
    ef1[p] = __builtin_amdgcn_exp2f(trans[31 * TAGS + (16 + 4 * q + p)] * LOG2E);
  }

  // State: alpha (exp2-space) in D-layout. alpha0 = delta(tag==30); tag 30 = 16+4*3+2.
  float a0[4] = {0.f, 0.f, 0.f, 0.f};
  float a1[4] = {0.f, 0.f, 0.f, 0.f};
  if (q == 3) a1[2] = 1.0f;
  float c2 = 0.0f;

  // B-operand (bf16, sigma k-order): element 6 (= u[3] low) is tag 30
  Frag8 B;
  B.u[0] = 0u; B.u[1] = 0u; B.u[2] = 0u;
  B.u[3] = (q == 3) ? 0x3F80u : 0u;

  const float4v zero = {0.f, 0.f, 0.f, 0.f};

  // feats prefetch ring, depth 8. f0: rows 4q..4q+3, f1: rows 16+4q..+3
  const float* fbase0 = feats + b * TAGS + 4 * q;
  const float* fbase1 = fbase0 + 16;
  float4v fr0[8], fr1[8];
  float   mk[8];
#pragma unroll
  for (int d = 0; d < 8; ++d) {
    fr0[d] = *(const float4v*)(fbase0 + d * (BATCH * TAGS));
    fr1[d] = *(const float4v*)(fbase1 + d * (BATCH * TAGS));
    mk[d]  = mask[d * BATCH + b];
  }

#pragma unroll 8
  for (int t = 0; t < SEQ; ++t) {
    const int slot = t & 7;
    const float4v f0 = fr0[slot];
    const float4v f1 = fr1[slot];
    const float   m  = mk[slot];
    if (t + 8 < SEQ) {
      fr0[slot] = *(const float4v*)(fbase0 + (t + 8) * (BATCH * TAGS));
      fr1[slot] = *(const float4v*)(fbase1 + (t + 8) * (BATCH * TAGS));
      mk[slot]  = mask[(t + 8) * BATCH + b];
    }

    // D = E * A  (two independent MFMAs, j-halves)
    float4v d0 = __builtin_amdgcn_mfma_f32_16x16x32_bf16(e0.v, B.v, zero, 0, 0, 0);
    float4v d1 = __builtin_amdgcn_mfma_f32_16x16x32_bf16(e1.v, B.v, zero, 0, 0, 0);

    // scale by 2^feat2, blend with mask (a += m*(new-a): exact for m in {0,1} up to 1 ulp)
#pragma unroll
    for (int p = 0; p < 4; ++p) {
      float n0 = d0[p] * __builtin_amdgcn_exp2f(f0[p] * LOG2E);
      float n1 = d1[p] * __builtin_amdgcn_exp2f(f1[p] * LOG2E);
      a0[p] = fmaf(m, n0 - a0[p], a0[p]);
      a1[p] = fmaf(m, n1 - a1[p], a1[p]);
    }

    if ((slot & 3) == 3) {
      // renorm by exact power of two: no rcp/log2 approx error
      float mx = fmaxf(fmaxf(fmaxf(a0[0], a0[1]), fmaxf(a0[2], a0[3])),
                       fmaxf(fmaxf(a1[0], a1[1]), fmaxf(a1[2], a1[3])));
      mx = fmaxf(mx, __shfl_xor(mx, 16, 64));
      mx = fmaxf(mx, __shfl_xor(mx, 32, 64));
      int ex = (int)((__float_as_uint(mx) >> 23) & 0xFFu) - 127;
      float scl = __uint_as_float((unsigned)(127 - ex) << 23);  // 2^-ex
#pragma unroll
      for (int p = 0; p < 4; ++p) { a0[p] *= scl; a1[p] *= scl; }
      c2 += (float)ex;
    }

    // repack next B-operand: lane's own D values ARE its B slots (sigma trick)
    B.u[0] = pk_bf16(a0[0], a0[1]);
    B.u[1] = pk_bf16(a0[2], a0[3]);
    B.u[2] = pk_bf16(a1[0], a1[1]);
    B.u[3] = pk_bf16(a1[2], a1[3]);
  }

  // epilogue: out[b] = ln2 * (c2 + log2( sum_j A[j,b] * 2^(trans2[31][j]) ))
  float v = a0[0] * ef0[0] + a0[1] * ef0[1] + a0[2] * ef0[2] + a0[3] * ef0[3]
          + a1[0] * ef1[0] + a1[1] * ef1[1] + a1[2] * ef1[2] + a1[3] * ef1[3];
  v += __shfl_xor(v, 16, 64);
  v += __shfl_xor(v, 32, 64);
  float res = LN2 * (c2 + __builtin_amdgcn_logf(v));
  if (q == 0) out[b] = res;
}

extern "C" void kernel_launch(void* const* d_in, const int* in_sizes, int n_in,
                              void* d_out, int out_size, void* d_ws, size_t ws_size,
                              hipStream_t stream) {
  const float* feats = (const float*)d_in[0];
  const float* mask  = (const float*)d_in[1];
  const float* trans = (const float*)d_in[2];
  float* out = (float*)d_out;
  dim3 grid(BATCH / 16);  // 64 blocks, 1 wave each (16 batches/wave)
  dim3 block(64);
  hipLaunchKernelGGL(crf_mfma, grid, block, 0, stream, feats, mask, trans, out);
}